// Round 5
// baseline (18809.003 us; speedup 1.0000x reference)
//
#include <hip/hip_runtime.h>

#define BATCH  4096
#define HID    1024
#define NOUT   64
#define TSTEPS 25
#define KA2    1280   // 64 (y_prev) + 128 (static) + 1024 (h1) + 64 zero-pad -> K % 64 == 0
#define KB     2048   // 1024 (h1) + 1024 (h2)
#define LDY    1600   // TSTEPS * NOUT
#define NBLK   256

typedef __attribute__((ext_vector_type(8))) __bf16 bf16x8;
typedef __attribute__((ext_vector_type(4))) float  floatx4;

__device__ __forceinline__ unsigned short f2bf(float f) {
    union { float f; unsigned u; } v; v.f = f;
    unsigned r = v.u + 0x7fffu + ((v.u >> 16) & 1u);
    return (unsigned short)(r >> 16);
}
__device__ __forceinline__ float rcpf(float x) { return __builtin_amdgcn_rcpf(x); }
__device__ __forceinline__ float sigmf(float x) { return rcpf(1.0f + __expf(-x)); }
__device__ __forceinline__ float tanh_fast(float x) {
    float ax = fabsf(x);
    float e  = __expf(-2.0f * ax);
    float t  = (1.0f - e) * rcpf(1.0f + e);
    return copysignf(t, x);
}

#define GLDS16(gp, lp) __builtin_amdgcn_global_load_lds( \
    (const __attribute__((address_space(1))) void*)(gp), \
    (__attribute__((address_space(3))) void*)(lp), 16, 0, 0)

#define SB() __builtin_amdgcn_sched_barrier(0)

// Device-scope sense-reversing grid barrier. Requires all 256 blocks
// co-resident (1 block/CU enforced by 128 KB LDS; cooperative launch
// validates). Per-wave __threadfence() on both sides: release drains each
// wave's own stores + L2 writeback (cross-XCD visibility); acquire
// invalidates stale L1/L2 lines. This replicates what dispatch boundaries
// cost today — no new traffic, only the CPU/command-processor gap removed.
__device__ __forceinline__ void gridbar(unsigned* bar)
{
    __threadfence();          // release: vmcnt drain + wb to coherent point
    __syncthreads();
    if (threadIdx.x == 0) {
        unsigned gen = __hip_atomic_load(bar + 1, __ATOMIC_RELAXED, __HIP_MEMORY_SCOPE_AGENT);
        unsigned arr = __hip_atomic_fetch_add(bar, 1u, __ATOMIC_ACQ_REL, __HIP_MEMORY_SCOPE_AGENT);
        if (arr == NBLK - 1) {
            __hip_atomic_store(bar, 0u, __ATOMIC_RELAXED, __HIP_MEMORY_SCOPE_AGENT);
            __hip_atomic_store(bar + 1, gen + 1u, __ATOMIC_RELEASE, __HIP_MEMORY_SCOPE_AGENT);
        } else {
            while (__hip_atomic_load(bar + 1, __ATOMIC_ACQUIRE, __HIP_MEMORY_SCOPE_AGENT) == gen)
                __builtin_amdgcn_s_sleep(8);
        }
    }
    __syncthreads();
    __threadfence();          // acquire: invalidate caches for fresh reads
}

// v12 = v11's fused GEMM+LSTM-cell body, verbatim, as a device function.
// (2-tiles-ahead staging, 4-phase counted vmcnt(6), phase-split MFMA,
// register-prefetch one phase ahead, epilogue cell/bias prefetch.)
__device__ __attribute__((always_inline)) void gate_gemm_body(
    char* smem, const int id,
    const unsigned short* __restrict__ X, int K,
    const unsigned short* __restrict__ W,
    const float* __restrict__ ginit,
    float* __restrict__ cell,
    unsigned short* __restrict__ d1, int ld1, int off1,
    unsigned short* __restrict__ d2, int ld2, int off2,
    float* __restrict__ dfp)
{
    const int tid  = threadIdx.x;
    const int lane = tid & 63;
    const int w    = tid >> 6;          // 0..7
    const int ql   = lane >> 4;         // 0..3 (K-chunk group of the frag)
    const int lr   = lane & 15;
    const int wr   = w >> 2;            // 0..1: 64-row half of the quadrant's 128
    const int wc   = w & 3;             // 0..3: 32-col slice of the quadrant's 128

    // XCD-aware swizzle (8 XCDs round-robin on flat block id)
    const int xcd = id & 7;
    const int c   = id >> 3;
    const int bx  = (xcd & 3) * 4 + (c & 3);
    const int by  = (xcd >> 2) * 8 + (c >> 2);
    const int m0  = bx * 256;
    const int j0  = by * 64;

    // staging: half-tile slot s = w*128 + lane (+64 for e=1)
    const int s0  = w * 128 + lane;
    const int r0  = s0 >> 3;
    const int kc0 = (s0 & 7) ^ (r0 & 7);
    const unsigned sOff = (unsigned)s0 * 16;
    const unsigned short* sA[2];
    const unsigned short* sB[2];
    sA[0] = X + (size_t)(m0 + r0) * K + kc0 * 8;
    sA[1] = X + (size_t)(m0 + 128 + r0) * K + kc0 * 8;
    {
        const int nb0 = r0, nb1 = 128 + r0;    // B rows = gate-interleaved cols
        sB[0] = W + (size_t)((nb0 & 3) * HID + j0 + (nb0 >> 2)) * K + kc0 * 8;
        sB[1] = W + (size_t)((nb1 & 3) * HID + j0 + (nb1 >> 2)) * K + kc0 * 8;
    }

#define STAGE_A(h, tt, p) do { \
    const unsigned short* _s = sA[h] + (size_t)(tt) * 64; \
    char* _d = smem + (p) + (h) * 16384 + sOff; \
    GLDS16(_s, _d); \
    GLDS16(_s + 8 * (size_t)K, _d + 1024); \
} while (0)

#define STAGE_B(h, tt, p) do { \
    const unsigned short* _s = sB[h] + (size_t)(tt) * 64; \
    char* _d = smem + (p) + 32768 + (h) * 16384 + sOff; \
    GLDS16(_s, _d); \
    GLDS16(_s + 2 * (size_t)K, _d + 1024); \
} while (0)

    unsigned offA[4], offB[2];
#pragma unroll
    for (int fi = 0; fi < 4; ++fi) {
        int r = wr * 64 + fi * 16 + lr;
        offA[fi] = (unsigned)((r * 8 + (ql ^ (r & 7))) * 16);
    }
#pragma unroll
    for (int fj = 0; fj < 2; ++fj) {
        int r = wc * 32 + fj * 16 + lr;
        offB[fj] = (unsigned)(32768 + (r * 8 + (ql ^ (r & 7))) * 16);
    }

#define LOAD_A(AV, BASE) do { \
    const char* _ab = smem + (BASE); \
    _Pragma("unroll") \
    for (int fi = 0; fi < 4; ++fi) { \
        AV[fi][0] = *(const bf16x8*)(_ab + offA[fi]); \
        AV[fi][1] = *(const bf16x8*)(_ab + (offA[fi] ^ 64u)); \
    } \
} while (0)

#define LOAD_B(BV, BASE) do { \
    const char* _bb = smem + (BASE); \
    _Pragma("unroll") \
    for (int fj = 0; fj < 2; ++fj) { \
        BV[fj][0] = *(const bf16x8*)(_bb + offB[fj]); \
        BV[fj][1] = *(const bf16x8*)(_bb + (offB[fj] ^ 64u)); \
    } \
} while (0)

#define MFMA_PART(Q, AV, BV, F0, F1) do { \
    __builtin_amdgcn_s_setprio(1); \
    _Pragma("unroll") \
    for (int fi = (F0); fi < (F1); ++fi) \
    _Pragma("unroll") \
    for (int fj = 0; fj < 2; ++fj) \
    _Pragma("unroll") \
    for (int kk = 0; kk < 2; ++kk) \
        acc[Q][fi][fj] = __builtin_amdgcn_mfma_f32_16x16x32_bf16( \
            AV[fi][kk], BV[fj][kk], acc[Q][fi][fj], 0, 0, 0); \
    __builtin_amdgcn_s_setprio(0); \
} while (0)

    floatx4 acc[4][4][2];   // q: 0=(A0,B0) 1=(A0,B1) 2=(A1,B1) 3=(A1,B0)
#pragma unroll
    for (int q = 0; q < 4; ++q)
#pragma unroll
        for (int i = 0; i < 4; ++i)
#pragma unroll
            for (int j = 0; j < 2; ++j)
                acc[q][i][j] = floatx4{0.f, 0.f, 0.f, 0.f};

    const int NT = K >> 6;

    bf16x8 av0[4][2], av1[4][2], bv0[2][2], bv1[2][2];

    // prologue: tile0 -> buf0, tile1 -> buf1
    STAGE_B(1, 0, 0); STAGE_A(1, 0, 0); STAGE_A(0, 0, 0); STAGE_B(0, 0, 0);
    STAGE_B(1, 1, 65536); STAGE_A(1, 1, 65536); STAGE_A(0, 1, 65536); STAGE_B(0, 1, 65536);
    asm volatile("s_waitcnt vmcnt(8)");
    __builtin_amdgcn_s_barrier();
    SB();
    LOAD_A(av0, 0);
    LOAD_B(bv0, 0);
    LOAD_B(bv1, 16384);
    SB();

    int par = 0;
    for (int t = 0; t < NT; ++t) {
        const int cur = par << 16;
        const int np  = cur ^ 65536;
        const int t2  = (t + 2 < NT) ? t + 2 : NT - 1;
        // P0: Q0 (av0 x bv0) | av1 <- cur.A1(t) | stage B1(t+2)->cur
        __builtin_amdgcn_s_barrier();
        SB();
        MFMA_PART(0, av0, bv0, 0, 1);
        SB();
        LOAD_A(av1, cur + 16384);
        STAGE_B(1, t2, cur);
        SB();
        MFMA_PART(0, av0, bv0, 1, 4);
        SB();
        // P1: Q1 (av0 x bv1) | stage A1(t+2)->cur
        __builtin_amdgcn_s_barrier();
        SB();
        MFMA_PART(1, av0, bv1, 0, 1);
        SB();
        STAGE_A(1, t2, cur);
        SB();
        MFMA_PART(1, av0, bv1, 1, 4);
        SB();
        // P2: Q2 (av1 x bv1) | av0 <- np.A0(t+1) | stage A0(t+2)->cur
        asm volatile("s_waitcnt vmcnt(6)");
        __builtin_amdgcn_s_barrier();
        SB();
        MFMA_PART(2, av1, bv1, 0, 1);
        SB();
        LOAD_A(av0, np);
        STAGE_A(0, t2, cur);
        SB();
        MFMA_PART(2, av1, bv1, 1, 4);
        SB();
        // P3: Q3 (av1 x bv0) | bv1 <- np.B1(t+1) | stage B0(t+2)->cur
        asm volatile("s_waitcnt vmcnt(6)");
        __builtin_amdgcn_s_barrier();
        SB();
        MFMA_PART(3, av1, bv0, 0, 1);
        SB();
        LOAD_B(bv1, np + 16384);
        STAGE_B(0, t2, cur);
        SB();
        MFMA_PART(3, av1, bv0, 1, 4);
        SB();
        LOAD_B(bv0, np);
        par ^= 1;
    }

    asm volatile("s_waitcnt vmcnt(0)");
    __builtin_amdgcn_s_barrier();

    // epilogue: per-wave private scratch, padded stride 36
    float* scratch = (float*)(void*)smem + w * 640;
    const int jj   = lane & 7;
    const int rsel = lane >> 3;

    float  cpre[4][4][2];
    float4 gi4[4];
#pragma unroll
    for (int qd = 0; qd < 4; ++qd) {
        const int qa = (qd >= 2) ? 1 : 0;
        const int qb = (qd == 1 || qd == 2) ? 1 : 0;
        const int rowbase = m0 + qa * 128 + wr * 64;
        const int jg = j0 + qb * 32 + wc * 8 + jj;
        gi4[qd] = *(const float4*)(ginit + (size_t)jg * 4);
#pragma unroll
        for (int fi = 0; fi < 4; ++fi)
#pragma unroll
            for (int p = 0; p < 2; ++p)
                cpre[qd][fi][p] = cell[(size_t)(rowbase + fi * 16 + rsel + p * 8) * HID + jg];
    }

#pragma unroll
    for (int qd = 0; qd < 4; ++qd) {
        const int qa = (qd >= 2) ? 1 : 0;
        const int qb = (qd == 1 || qd == 2) ? 1 : 0;
        const int rowbase = m0 + qa * 128 + wr * 64;
        const int jg = j0 + qb * 32 + wc * 8 + jj;
        const float4 gi = gi4[qd];
#pragma unroll
        for (int fi = 0; fi < 4; ++fi) {
#pragma unroll
            for (int fj = 0; fj < 2; ++fj)
#pragma unroll
                for (int r = 0; r < 4; ++r)
                    scratch[(ql * 4 + r) * 36 + fj * 16 + lr] = acc[qd][fi][fj][r];
            asm volatile("" ::: "memory");
#pragma unroll
            for (int p = 0; p < 2; ++p) {
                const int row = rsel + p * 8;
                const float4 g = *(const float4*)(scratch + row * 36 + jj * 4);
                const int b = rowbase + fi * 16 + row;
                float iv = sigmf(g.x + gi.x);
                float fv = sigmf(g.y + gi.y);
                float gv = tanh_fast(g.z + gi.z);
                float ov = sigmf(g.w + gi.w);
                size_t ci = (size_t)b * HID + jg;
                float cn = fv * cpre[qd][fi][p] + iv * gv;
                cell[ci] = cn;
                float hv = ov * tanh_fast(cn);
                unsigned short hb = f2bf(hv);
                d1[(size_t)b * ld1 + off1 + jg] = hb;
                if (d2)  d2[(size_t)b * ld2 + off2 + jg] = hb;
                if (dfp) dfp[(size_t)b * HID + jg] = hv;
            }
            asm volatile("" ::: "memory");
        }
    }
#undef MFMA_PART
#undef LOAD_A
#undef LOAD_B
#undef STAGE_A
#undef STAGE_B
}

// out phase: y = h2 @ WoutT + bout; 512 threads, 16 batch rows per block.
__device__ __attribute__((always_inline)) void out_body(
    char* smemc, const int id,
    const float* __restrict__ h2, const float* __restrict__ wt,
    const float* __restrict__ bout, float* __restrict__ y,
    unsigned short* __restrict__ xn)
{
    float* hl = (float*)(void*)smemc;   // 64 KB: 16 h2 rows
    const int tid = threadIdx.x;
    const int b0 = id * 16;
#pragma unroll
    for (int r = 0; r < 8; ++r) {
        int f4 = r * 512 + tid;
        *(float4*)(hl + f4 * 4) = *(const float4*)(h2 + (size_t)b0 * 1024 + f4 * 4);
    }
    __syncthreads();
    const int o  = tid & 63;
    const int wv = tid >> 6;          // 0..7, 2 rows each
    float a0 = 0.f, a1 = 0.f;
#pragma unroll 8
    for (int k = 0; k < 1024; ++k) {
        float wvv = wt[k * 64 + o];
        const float* hr = hl + (wv * 2) * 1024 + k;
        a0 += hr[0]    * wvv;
        a1 += hr[1024] * wvv;
    }
    float bo = bout[o];
    int b = b0 + wv * 2;
    float y0 = a0 + bo, y1 = a1 + bo;
    y[(size_t)b * LDY + o] = y0;
    y[(size_t)(b + 1) * LDY + o] = y1;
    xn[(size_t)b * KA2 + o] = f2bf(y0);
    xn[(size_t)(b + 1) * KA2 + o] = f2bf(y1);
}

// Persistent kernel: all 25 steps (L0, L1, out) with grid barriers between
// phases. C1/C2 are block-private across steps (same (b,j) partition every
// step) -> no barrier needed for them; barriers cover h1/h2/y handoffs.
__global__ __launch_bounds__(512, 2) void lstm_persistent(
    const unsigned short* __restrict__ W0, const unsigned short* __restrict__ W1,
    const float* __restrict__ B0b, const float* __restrict__ B1b,
    const float* __restrict__ WoT, const float* __restrict__ bout,
    float* __restrict__ C1, float* __restrict__ C2, float* __restrict__ H2f,
    unsigned short* __restrict__ X0a, unsigned short* __restrict__ X0b,
    unsigned short* __restrict__ X1a, unsigned short* __restrict__ X1b,
    float* __restrict__ out, unsigned* bar)
{
    __shared__ __align__(16) char smem[131072];
    const int id = blockIdx.y * 16 + blockIdx.x;
    for (int t = 0; t < TSTEPS; ++t) {
        unsigned short* X0c = (t & 1) ? X0b : X0a;
        unsigned short* X0n = (t & 1) ? X0a : X0b;
        unsigned short* X1c = (t & 1) ? X1b : X1a;
        unsigned short* X1n = (t & 1) ? X1a : X1b;
        gate_gemm_body(smem, id, X0c, KA2, W0, B0b, C1,
                       X1c, KB, 0, X0n, KA2, 192, nullptr);
        gridbar(bar);
        gate_gemm_body(smem, id, X1c, KB, W1, B1b, C2,
                       X1n, KB, 1024, nullptr, 0, 0, H2f);
        gridbar(bar);
        out_body(smem, id, H2f, WoT, bout, out + t * NOUT, X0n);
        gridbar(bar);
    }
}

// ---- fallback wrappers (used only if cooperative launch is rejected) ----
__global__ __launch_bounds__(512, 2) void lstm_gate_gemm_k(
    const unsigned short* __restrict__ X, int K,
    const unsigned short* __restrict__ W,
    const float* __restrict__ ginit, float* __restrict__ cell,
    unsigned short* __restrict__ d1, int ld1, int off1,
    unsigned short* __restrict__ d2, int ld2, int off2,
    float* __restrict__ dfp)
{
    __shared__ __align__(16) char smem[131072];
    const int id = blockIdx.y * 16 + blockIdx.x;
    gate_gemm_body(smem, id, X, K, W, ginit, cell, d1, ld1, off1, d2, ld2, off2, dfp);
}

__global__ __launch_bounds__(512) void out_gemm_k(
    const float* __restrict__ h2, const float* __restrict__ wt,
    const float* __restrict__ bout, float* __restrict__ y,
    unsigned short* __restrict__ xn)
{
    __shared__ __align__(16) char smem[65536];
    out_body(smem, blockIdx.x, h2, wt, bout, y, xn);
}

// WoutT[k*64+o] = Wout[o*1024+k]
__global__ void build_woutT(const float* __restrict__ wout, float* __restrict__ wt)
{
    int idx = blockIdx.x * 256 + threadIdx.x;   // 65536
    int o = idx & 63, k = idx >> 6;
    wt[idx] = wout[(size_t)o * 1024 + k];
}

// interleaved bias: out[j*4+gate] = a[gate*1024+j] + b[gate*1024+j]
__global__ void build_bias(const float* __restrict__ a, const float* __restrict__ b,
                           float* __restrict__ o)
{
    int idx = blockIdx.x * 256 + threadIdx.x;   // 4096
    int gate = idx & 3, j = idx >> 2;
    int n = gate * 1024 + j;
    o[idx] = a[n] + b[n];
}

// W0[n] (KA2=1280): [0:64]=W_ih0[n][128:192], [64:192]=W_ih0[n][0:128],
// [192:1216]=W_hh0[n][:], [1216:1280]=0
__global__ __launch_bounds__(256) void build_w0(
    const float* __restrict__ wih, const float* __restrict__ whh,
    unsigned short* __restrict__ w0)
{
    int idx = blockIdx.x * 256 + threadIdx.x;   // 4096*320 exact
    int n = idx / 320;
    int c = (idx - n * 320) * 4;
    float4 v = {0.f, 0.f, 0.f, 0.f};
    if (c < 64)        v = *(const float4*)(wih + (size_t)n * 192 + 128 + c);
    else if (c < 192)  v = *(const float4*)(wih + (size_t)n * 192 + (c - 64));
    else if (c < 1216) v = *(const float4*)(whh + (size_t)n * 1024 + (c - 192));
    ushort4 o;
    o.x = f2bf(v.x); o.y = f2bf(v.y); o.z = f2bf(v.z); o.w = f2bf(v.w);
    *(ushort4*)(w0 + (size_t)n * KA2 + c) = o;
}

// W1[n][0:1024] = W_ih1[n][:], W1[n][1024:2048] = W_hh1[n][:]
__global__ __launch_bounds__(256) void build_w1(
    const float* __restrict__ wih, const float* __restrict__ whh,
    unsigned short* __restrict__ w1)
{
    int idx = blockIdx.x * 256 + threadIdx.x;   // 4096*512 exact
    int n = idx >> 9;
    int c = (idx & 511) * 4;
    float4 v;
    if (c < 1024) v = *(const float4*)(wih + (size_t)n * 1024 + c);
    else          v = *(const float4*)(whh + (size_t)n * 1024 + (c - 1024));
    ushort4 o;
    o.x = f2bf(v.x); o.y = f2bf(v.y); o.z = f2bf(v.z); o.w = f2bf(v.w);
    *(ushort4*)(w1 + (size_t)n * KB + c) = o;
}

// static bf16 into X0a and X0b cols 64..191
__global__ __launch_bounds__(256) void build_x0static(
    const float* __restrict__ stat, unsigned short* __restrict__ xa,
    unsigned short* __restrict__ xb)
{
    int idx = blockIdx.x * 256 + threadIdx.x;   // 4096*32 exact
    int b = idx >> 5;
    int c = (idx & 31) * 4;
    float4 v = *(const float4*)(stat + (size_t)b * 128 + c);
    ushort4 o;
    o.x = f2bf(v.x); o.y = f2bf(v.y); o.z = f2bf(v.z); o.w = f2bf(v.w);
    *(ushort4*)(xa + (size_t)b * KA2 + 64 + c) = o;
    *(ushort4*)(xb + (size_t)b * KA2 + 64 + c) = o;
}

extern "C" void kernel_launch(void* const* d_in, const int* in_sizes, int n_in,
                              void* d_out, int out_size, void* d_ws, size_t ws_size,
                              hipStream_t stream)
{
    (void)in_sizes; (void)n_in; (void)out_size; (void)ws_size;
    const float* static_in = (const float*)d_in[0];
    const float* Wih0 = (const float*)d_in[1];
    const float* Whh0 = (const float*)d_in[2];
    const float* bih0 = (const float*)d_in[3];
    const float* bhh0 = (const float*)d_in[4];
    const float* Wih1 = (const float*)d_in[5];
    const float* Whh1 = (const float*)d_in[6];
    const float* bih1 = (const float*)d_in[7];
    const float* bhh1 = (const float*)d_in[8];
    const float* Wout = (const float*)d_in[9];
    const float* bout = (const float*)d_in[10];
    float* out = (float*)d_out;

    char* p = (char*)d_ws;
    size_t off = 0;
    auto take = [&](size_t n) { char* r = p + off; off += (n + 255) & ~(size_t)255; return r; };

    unsigned short* W0   = (unsigned short*)take((size_t)4096 * KA2 * 2);
    unsigned short* W1   = (unsigned short*)take((size_t)4096 * KB * 2);
    float*          B1b  = (float*)take(4096 * 4);
    float*          B0b  = (float*)take(4096 * 4);
    float*          WoT  = (float*)take((size_t)1024 * 64 * 4);
    float*          H2f  = (float*)take((size_t)BATCH * HID * 4);
    float*          C1   = (float*)take((size_t)BATCH * HID * 4);
    float*          C2   = (float*)take((size_t)BATCH * HID * 4);
    unsigned short* X0a  = (unsigned short*)take((size_t)BATCH * KA2 * 2);
    unsigned short* X0b  = (unsigned short*)take((size_t)BATCH * KA2 * 2);
    unsigned short* X1a  = (unsigned short*)take((size_t)BATCH * KB * 2);
    unsigned short* X1b  = (unsigned short*)take((size_t)BATCH * KB * 2);
    unsigned*       bar  = (unsigned*)take(256);

    hipMemsetAsync(C1, 0, (size_t)BATCH * HID * 4, stream);
    hipMemsetAsync(C2, 0, (size_t)BATCH * HID * 4, stream);
    hipMemsetAsync(X0a, 0, (size_t)BATCH * KA2 * 2, stream);  // y0 = h1_0 = 0, pad = 0
    hipMemsetAsync(X0b, 0, (size_t)BATCH * KA2 * 2, stream);
    hipMemsetAsync(X1a, 0, (size_t)BATCH * KB * 2, stream);   // h2_0 = 0
    hipMemsetAsync(bar, 0, 256, stream);

    build_w0<<<5120, 256, 0, stream>>>(Wih0, Whh0, W0);
    build_w1<<<8192, 256, 0, stream>>>(Wih1, Whh1, W1);
    build_woutT<<<256, 256, 0, stream>>>(Wout, WoT);
    build_bias<<<16, 256, 0, stream>>>(bih0, bhh0, B0b);
    build_bias<<<16, 256, 0, stream>>>(bih1, bhh1, B1b);
    build_x0static<<<512, 256, 0, stream>>>(static_in, X0a, X0b);

    // single persistent cooperative dispatch for all 25 steps
    const float* bout_l = bout;
    void* kargs[] = {
        (void*)&W0, (void*)&W1, (void*)&B0b, (void*)&B1b, (void*)&WoT,
        (void*)&bout_l, (void*)&C1, (void*)&C2, (void*)&H2f,
        (void*)&X0a, (void*)&X0b, (void*)&X1a, (void*)&X1b,
        (void*)&out, (void*)&bar
    };
    hipError_t e = hipLaunchCooperativeKernel(
        reinterpret_cast<void*>(lstm_persistent),
        dim3(16, 16), dim3(512, 1, 1), kargs, 0, stream);

    if (e != hipSuccess) {
        // fallback: per-step dispatch sequence (v11 behavior)
        dim3 grid(16, 16);
        for (int t = 0; t < TSTEPS; ++t) {
            unsigned short* X0c = (t & 1) ? X0b : X0a;
            unsigned short* X0n = (t & 1) ? X0a : X0b;
            unsigned short* X1c = (t & 1) ? X1b : X1a;
            unsigned short* X1n = (t & 1) ? X1a : X1b;
            lstm_gate_gemm_k<<<grid, 512, 0, stream>>>(X0c, KA2, W0, B0b, C1,
                                                       X1c, KB, 0, X0n, KA2, 192, nullptr);
            lstm_gate_gemm_k<<<grid, 512, 0, stream>>>(X1c, KB, W1, B1b, C2,
                                                       X1n, KB, 1024, nullptr, 0, 0, H2f);
            out_gemm_k<<<256, 512, 0, stream>>>(H2f, WoT, bout, out + t * NOUT, X0n);
        }
    }
}

// Round 6
// 4888.045 us; speedup vs baseline: 3.8480x; 3.8480x over previous
//
#include <hip/hip_runtime.h>

#define BATCH  4096
#define HID    1024
#define NOUT   64
#define TSTEPS 25
#define KA2    1280   // 64 (y_prev) + 128 (static) + 1024 (h1) + 64 zero-pad -> K % 64 == 0
#define KB     2048   // 1024 (h1) + 1024 (h2)
#define LDY    1600   // TSTEPS * NOUT

typedef __attribute__((ext_vector_type(8))) __bf16 bf16x8;
typedef __attribute__((ext_vector_type(4))) float  floatx4;

__device__ __forceinline__ unsigned short f2bf(float f) {
    union { float f; unsigned u; } v; v.f = f;
    unsigned r = v.u + 0x7fffu + ((v.u >> 16) & 1u);
    return (unsigned short)(r >> 16);
}
__device__ __forceinline__ float rcpf(float x) { return __builtin_amdgcn_rcpf(x); }
__device__ __forceinline__ float sigmf(float x) { return rcpf(1.0f + __expf(-x)); }
__device__ __forceinline__ float tanh_fast(float x) {
    float ax = fabsf(x);
    float e  = __expf(-2.0f * ax);
    float t  = (1.0f - e) * rcpf(1.0f + e);
    return copysignf(t, x);
}

#define GLDS16(gp, lp) __builtin_amdgcn_global_load_lds( \
    (const __attribute__((address_space(1))) void*)(gp), \
    (__attribute__((address_space(3))) void*)(lp), 16, 0, 0)

#define SB() __builtin_amdgcn_sched_barrier(0)

// v13: B-OPERANDS DIRECT FROM GLOBAL (L2), A-only LDS. v12 post-mortem:
// persistent+per-wave-threadfence invalidated L2 every phase (FETCH 2.9->5.2GB,
// 5x regression) -> reverted to v11 launch structure. v11's residual wall
// (4200 cyc/tile vs 2483 MFMA floor) is the LDS pipe: 192KB reads + 64KB DMA
// writes/tile/CU ~= 2800 cyc. Removing B from LDS: reads 128KB + writes 32KB
// ~= 1750 cyc < MFMA floor -> MFMA-bound. B-frags (16 rows x 64B contiguous
// per instr) load from L2-resident weights, double-buffered in regs (+32 VGPR;
// total ~250 <= 256 @ 2 waves/SIMD).
//
// LDS: [buf0|buf1] x 32KB, A-halves only (A0 @0, A1 @16K per buf).
// Tile = 4 phases (A-half x fi-pair), 16 MFMA each; ds-reads one phase ahead;
// ONE barrier/tile (P3). vmcnt FIFO (audited): per tile issue
// P1:BL4(B t+1,bh0) P2:BL4(bh1) P3:GLDS4(A t+2). Steady state: P0-top 4
// outstanding [A(t+1)]; P3-top vmcnt(8) drains A(t+1) (cross-wave: each wave
// waits own count BEFORE barrier); B consumption waits are compiler-counted
// (plain loads; LLVM models global_load_lds in the vmcnt FIFO).
// Quadrant map q: 0=(A0,B0) 1=(A0,B1) 2=(A1,B1) 3=(A1,B0) (epilogue-compatible).
__global__ __launch_bounds__(512, 2) void lstm_gate_gemm(
    const unsigned short* __restrict__ X, int K,
    const unsigned short* __restrict__ W,
    const float* __restrict__ ginit,
    float* __restrict__ cell,
    unsigned short* __restrict__ d1, int ld1, int off1,
    unsigned short* __restrict__ d2, int ld2, int off2,
    float* __restrict__ dfp)
{
    __shared__ __align__(16) char smem[65536];

    const int tid  = threadIdx.x;
    const int lane = tid & 63;
    const int w    = tid >> 6;          // 0..7
    const int ql   = lane >> 4;         // 0..3 (K-chunk group of the frag)
    const int lr   = lane & 15;
    const int wr   = w >> 2;            // 0..1: 64-row half of the 128-row A-half
    const int wc   = w & 3;             // 0..3: 32-col slice of the 128-col B-half

    // XCD-aware swizzle (8 XCDs round-robin on flat block id)
    const int id  = blockIdx.y * 16 + blockIdx.x;
    const int xcd = id & 7;
    const int c   = id >> 3;
    const int bx  = (xcd & 3) * 4 + (c & 3);
    const int by  = (xcd >> 2) * 8 + (c >> 2);
    const int m0  = bx * 256;
    const int j0  = by * 64;

    // ---- A staging: half-tile slot s = w*128 + lane (+64 for e=1)
    // slot s holds global chunk (row = s>>3, kc = (s&7)^(row&7)).
    const int s0  = w * 128 + lane;
    const int r0  = s0 >> 3;
    const int kc0 = (s0 & 7) ^ (r0 & 7);
    const unsigned sOff = (unsigned)s0 * 16;
    const unsigned short* sA[2];
    sA[0] = X + (size_t)(m0 + r0) * K + kc0 * 8;
    sA[1] = X + (size_t)(m0 + 128 + r0) * K + kc0 * 8;

#define STAGE_A(h, tt, p) do { \
    const unsigned short* _s = sA[h] + (size_t)(tt) * 64; \
    char* _d = smem + (p) + (h) * 16384 + sOff; \
    GLDS16(_s, _d); \
    GLDS16(_s + 8 * (size_t)K, _d + 1024); \
} while (0)

    // ---- A fragment ds_read offsets (relative to half region; kk=1 -> ^64)
    unsigned offA[4];
#pragma unroll
    for (int fi = 0; fi < 4; ++fi) {
        int r = wr * 64 + fi * 16 + lr;
        offA[fi] = (unsigned)((r * 8 + (ql ^ (r & 7))) * 16);
    }

    // ---- B global fragment pointers: i = bh*2+fj; B row nb (gate-interleaved
    // block col) -> W row (nb&3)*HID + j0 + (nb>>2); lane k-chunk ql*8.
    const unsigned short* bp[4];
#pragma unroll
    for (int i = 0; i < 4; ++i) {
        int nb = (i >> 1) * 128 + wc * 32 + (i & 1) * 16 + lr;
        int rowg = (nb & 3) * HID + j0 + (nb >> 2);
        bp[i] = W + (size_t)rowg * K + ql * 8;
    }

#define LOADP(DST, BOFF, FP) do { \
    const char* _p = smem + (BOFF); \
    _Pragma("unroll") \
    for (int fi2 = 0; fi2 < 2; ++fi2) { \
        DST[fi2][0] = *(const bf16x8*)(_p + offA[(FP) * 2 + fi2]); \
        DST[fi2][1] = *(const bf16x8*)(_p + (offA[(FP) * 2 + fi2] ^ 64u)); \
    } \
} while (0)

#define BL4(BN, BH, TN) do { \
    _Pragma("unroll") \
    for (int fj = 0; fj < 2; ++fj) \
    _Pragma("unroll") \
    for (int kk = 0; kk < 2; ++kk) \
        BN[BH][fj][kk] = *(const bf16x8*)(bp[(BH) * 2 + fj] + (size_t)(TN) * 64 + kk * 32); \
} while (0)

#define MFMAP(H, FP, AS, BS) do { \
    __builtin_amdgcn_s_setprio(1); \
    _Pragma("unroll") \
    for (int fi2 = 0; fi2 < 2; ++fi2) \
    _Pragma("unroll") \
    for (int bh = 0; bh < 2; ++bh) \
    _Pragma("unroll") \
    for (int fj = 0; fj < 2; ++fj) \
    _Pragma("unroll") \
    for (int kk = 0; kk < 2; ++kk) \
        acc[(H) ? (3 - bh) : bh][(FP) * 2 + fi2][fj] = \
            __builtin_amdgcn_mfma_f32_16x16x32_bf16( \
                AS[fi2][kk], BS[bh][fj][kk], \
                acc[(H) ? (3 - bh) : bh][(FP) * 2 + fi2][fj], 0, 0, 0); \
    __builtin_amdgcn_s_setprio(0); \
} while (0)

    floatx4 acc[4][4][2];
#pragma unroll
    for (int q = 0; q < 4; ++q)
#pragma unroll
        for (int i = 0; i < 4; ++i)
#pragma unroll
            for (int j = 0; j < 2; ++j)
                acc[q][i][j] = floatx4{0.f, 0.f, 0.f, 0.f};

    const int NT = K >> 6;   // 20 (L0) or 32 (L1), both even

    bf16x8 aA[2][2], aB[2][2];          // fi-pair x kk (16 VGPR each)
    bf16x8 bA[2][2][2], bB[2][2][2];    // bh x fj x kk (32 VGPR each)

    // ---- prologue: A(0)->buf0, B(0)->regs, A(1)->buf1.
    SB();
    STAGE_A(0, 0, 0); STAGE_A(1, 0, 0);
    SB();
    BL4(bA, 0, 0); BL4(bA, 1, 0);
    SB();
    STAGE_A(0, 1, 32768); STAGE_A(1, 1, 32768);
    SB();
    asm volatile("s_waitcnt vmcnt(12)");   // A(0) landed; B(0)+A(1) in flight
    __builtin_amdgcn_s_barrier();
    SB();
    LOADP(aA, 0, 0);                       // buf0.A0 fp0
    SB();

#define TILE(TT, BUF, NBUF, BC, BN) do { \
    const int t2 = ((TT) + 2 < NT) ? (TT) + 2 : NT - 1; \
    const int tn = ((TT) + 1 < NT) ? (TT) + 1 : NT - 1; \
    /* P0: MFMA h0 fp0 | read h0 fp1 */ \
    SB(); \
    LOADP(aB, (BUF), 1); \
    SB(); \
    MFMAP(0, 0, aA, BC); \
    /* P1: MFMA h0 fp1 | read h1 fp0 | BL B(t+1) bh0 */ \
    SB(); \
    LOADP(aA, (BUF) + 16384, 0); \
    BL4(BN, 0, tn); \
    SB(); \
    MFMAP(0, 1, aB, BC); \
    /* P2: MFMA h1 fp0 | read h1 fp1 | BL B(t+1) bh1 */ \
    SB(); \
    LOADP(aB, (BUF) + 16384, 1); \
    BL4(BN, 1, tn); \
    SB(); \
    MFMAP(1, 0, aA, BC); \
    /* P3: A(t+1) landed -> barrier; MFMA h1 fp1 | read next-tile h0 fp0 | stage A(t+2) */ \
    asm volatile("s_waitcnt vmcnt(8)"); \
    __builtin_amdgcn_s_barrier(); \
    SB(); \
    LOADP(aA, (NBUF), 0); \
    STAGE_A(0, t2, (BUF)); STAGE_A(1, t2, (BUF)); \
    SB(); \
    MFMAP(1, 1, aB, BC); \
} while (0)

    for (int t = 0; t < NT; t += 2) {
        TILE(t,     0,     32768, bA, bB);
        TILE(t + 1, 32768, 0,     bB, bA);
    }

    // ---- epilogue: drain tail DMAs before reusing LDS as scratch.
    asm volatile("s_waitcnt vmcnt(0)");
    __builtin_amdgcn_s_barrier();

    // Per-wave private scratch (2560 B), padded stride 36 floats -> float4
    // reads conflict-free. No cross-wave sharing => no barriers needed.
    float* scratch = (float*)(void*)smem + w * 640;
    const int jj   = lane & 7;
    const int rsel = lane >> 3;

    // Hoisted epilogue prefetch: cell + bias (operand regs dead here).
    float  cpre[4][4][2];
    float4 gi4[4];
#pragma unroll
    for (int qd = 0; qd < 4; ++qd) {
        const int qa = (qd >= 2) ? 1 : 0;
        const int qb = (qd == 1 || qd == 2) ? 1 : 0;
        const int rowbase = m0 + qa * 128 + wr * 64;
        const int jg = j0 + qb * 32 + wc * 8 + jj;
        gi4[qd] = *(const float4*)(ginit + (size_t)jg * 4);
#pragma unroll
        for (int fi = 0; fi < 4; ++fi)
#pragma unroll
            for (int p = 0; p < 2; ++p)
                cpre[qd][fi][p] = cell[(size_t)(rowbase + fi * 16 + rsel + p * 8) * HID + jg];
    }

#pragma unroll
    for (int qd = 0; qd < 4; ++qd) {
        const int qa = (qd >= 2) ? 1 : 0;
        const int qb = (qd == 1 || qd == 2) ? 1 : 0;
        const int rowbase = m0 + qa * 128 + wr * 64;
        const int jg = j0 + qb * 32 + wc * 8 + jj;
        const float4 gi = gi4[qd];
#pragma unroll
        for (int fi = 0; fi < 4; ++fi) {
            // 16x32 slab: C/D frag layout col=lane&15, row=ql*4+reg
#pragma unroll
            for (int fj = 0; fj < 2; ++fj)
#pragma unroll
                for (int r = 0; r < 4; ++r)
                    scratch[(ql * 4 + r) * 36 + fj * 16 + lr] = acc[qd][fi][fj][r];
            asm volatile("" ::: "memory");
#pragma unroll
            for (int p = 0; p < 2; ++p) {
                const int row = rsel + p * 8;
                const float4 g = *(const float4*)(scratch + row * 36 + jj * 4);
                const int b = rowbase + fi * 16 + row;
                float iv = sigmf(g.x + gi.x);
                float fv = sigmf(g.y + gi.y);
                float gv = tanh_fast(g.z + gi.z);
                float ov = sigmf(g.w + gi.w);
                size_t ci = (size_t)b * HID + jg;
                float cn = fv * cpre[qd][fi][p] + iv * gv;
                cell[ci] = cn;
                float hv = ov * tanh_fast(cn);
                unsigned short hb = f2bf(hv);
                d1[(size_t)b * ld1 + off1 + jg] = hb;
                if (d2)  d2[(size_t)b * ld2 + off2 + jg] = hb;
                if (dfp) dfp[(size_t)b * HID + jg] = hv;
            }
            asm volatile("" ::: "memory");
        }
    }
#undef TILE
#undef MFMAP
#undef BL4
#undef LOADP
#undef STAGE_A
}

// y = h2_f32 @ Wout^T + bout (fp32); WoutT layout wt[k*64+o]; h2 staged in LDS.
// 16 rows/block (256 blocks = 1/CU): halves device-wide WoT re-read traffic.
__global__ __launch_bounds__(256) void out_gemm(
    const float* __restrict__ h2, const float* __restrict__ wt,
    const float* __restrict__ bout, float* __restrict__ y,
    unsigned short* __restrict__ xn)
{
    __shared__ float hl[16 * 1024];   // 64 KB: 16 h2 rows
    const int tid = threadIdx.x;
    const int b0 = blockIdx.x * 16;
#pragma unroll
    for (int r = 0; r < 16; ++r) {
        int f4 = r * 256 + tid;
        *(float4*)(hl + f4 * 4) = *(const float4*)(h2 + (size_t)b0 * 1024 + f4 * 4);
    }
    __syncthreads();
    const int o  = tid & 63;
    const int wv = tid >> 6;          // 0..3, 4 rows each
    float a0 = 0.f, a1 = 0.f, a2 = 0.f, a3 = 0.f;
#pragma unroll 8
    for (int k = 0; k < 1024; ++k) {
        float wvv = wt[k * 64 + o];
        const float* hr = hl + (wv * 4) * 1024 + k;
        a0 += hr[0]    * wvv;
        a1 += hr[1024] * wvv;
        a2 += hr[2048] * wvv;
        a3 += hr[3072] * wvv;
    }
    float bo = bout[o];
    int b = b0 + wv * 4;
    float yv[4] = {a0 + bo, a1 + bo, a2 + bo, a3 + bo};
#pragma unroll
    for (int r = 0; r < 4; ++r) {
        y[(size_t)(b + r) * LDY + o] = yv[r];
        xn[(size_t)(b + r) * KA2 + o] = f2bf(yv[r]);
    }
}

// WoutT[k*64+o] = Wout[o*1024+k]
__global__ void build_woutT(const float* __restrict__ wout, float* __restrict__ wt)
{
    int idx = blockIdx.x * 256 + threadIdx.x;   // 65536
    int o = idx & 63, k = idx >> 6;
    wt[idx] = wout[(size_t)o * 1024 + k];
}

// interleaved bias: out[j*4+gate] = a[gate*1024+j] + b[gate*1024+j]
__global__ void build_bias(const float* __restrict__ a, const float* __restrict__ b,
                           float* __restrict__ o)
{
    int idx = blockIdx.x * 256 + threadIdx.x;   // 4096
    int gate = idx & 3, j = idx >> 2;
    int n = gate * 1024 + j;
    o[idx] = a[n] + b[n];
}

// W0[n] (KA2=1280): [0:64]=W_ih0[n][128:192], [64:192]=W_ih0[n][0:128],
// [192:1216]=W_hh0[n][:], [1216:1280]=0
__global__ __launch_bounds__(256) void build_w0(
    const float* __restrict__ wih, const float* __restrict__ whh,
    unsigned short* __restrict__ w0)
{
    int idx = blockIdx.x * 256 + threadIdx.x;   // 4096*320 exact
    int n = idx / 320;
    int c = (idx - n * 320) * 4;
    float4 v = {0.f, 0.f, 0.f, 0.f};
    if (c < 64)        v = *(const float4*)(wih + (size_t)n * 192 + 128 + c);
    else if (c < 192)  v = *(const float4*)(wih + (size_t)n * 192 + (c - 64));
    else if (c < 1216) v = *(const float4*)(whh + (size_t)n * 1024 + (c - 192));
    ushort4 o;
    o.x = f2bf(v.x); o.y = f2bf(v.y); o.z = f2bf(v.z); o.w = f2bf(v.w);
    *(ushort4*)(w0 + (size_t)n * KA2 + c) = o;
}

// W1[n][0:1024] = W_ih1[n][:], W1[n][1024:2048] = W_hh1[n][:]
__global__ __launch_bounds__(256) void build_w1(
    const float* __restrict__ wih, const float* __restrict__ whh,
    unsigned short* __restrict__ w1)
{
    int idx = blockIdx.x * 256 + threadIdx.x;   // 4096*512 exact
    int n = idx >> 9;
    int c = (idx & 511) * 4;
    float4 v;
    if (c < 1024) v = *(const float4*)(wih + (size_t)n * 1024 + c);
    else          v = *(const float4*)(whh + (size_t)n * 1024 + (c - 1024));
    ushort4 o;
    o.x = f2bf(v.x); o.y = f2bf(v.y); o.z = f2bf(v.z); o.w = f2bf(v.w);
    *(ushort4*)(w1 + (size_t)n * KB + c) = o;
}

// static bf16 into X0a and X0b cols 64..191
__global__ __launch_bounds__(256) void build_x0static(
    const float* __restrict__ stat, unsigned short* __restrict__ xa,
    unsigned short* __restrict__ xb)
{
    int idx = blockIdx.x * 256 + threadIdx.x;   // 4096*32 exact
    int b = idx >> 5;
    int c = (idx & 31) * 4;
    float4 v = *(const float4*)(stat + (size_t)b * 128 + c);
    ushort4 o;
    o.x = f2bf(v.x); o.y = f2bf(v.y); o.z = f2bf(v.z); o.w = f2bf(v.w);
    *(ushort4*)(xa + (size_t)b * KA2 + 64 + c) = o;
    *(ushort4*)(xb + (size_t)b * KA2 + 64 + c) = o;
}

extern "C" void kernel_launch(void* const* d_in, const int* in_sizes, int n_in,
                              void* d_out, int out_size, void* d_ws, size_t ws_size,
                              hipStream_t stream)
{
    (void)in_sizes; (void)n_in; (void)out_size; (void)ws_size;
    const float* static_in = (const float*)d_in[0];
    const float* Wih0 = (const float*)d_in[1];
    const float* Whh0 = (const float*)d_in[2];
    const float* bih0 = (const float*)d_in[3];
    const float* bhh0 = (const float*)d_in[4];
    const float* Wih1 = (const float*)d_in[5];
    const float* Whh1 = (const float*)d_in[6];
    const float* bih1 = (const float*)d_in[7];
    const float* bhh1 = (const float*)d_in[8];
    const float* Wout = (const float*)d_in[9];
    const float* bout = (const float*)d_in[10];
    float* out = (float*)d_out;

    char* p = (char*)d_ws;
    size_t off = 0;
    auto take = [&](size_t n) { char* r = p + off; off += (n + 255) & ~(size_t)255; return r; };

    unsigned short* W0   = (unsigned short*)take((size_t)4096 * KA2 * 2);
    unsigned short* W1   = (unsigned short*)take((size_t)4096 * KB * 2);
    float*          B1b  = (float*)take(4096 * 4);
    float*          B0b  = (float*)take(4096 * 4);
    float*          WoT  = (float*)take((size_t)1024 * 64 * 4);
    float*          H2f  = (float*)take((size_t)BATCH * HID * 4);
    float*          C1   = (float*)take((size_t)BATCH * HID * 4);
    float*          C2   = (float*)take((size_t)BATCH * HID * 4);
    unsigned short* X0a  = (unsigned short*)take((size_t)BATCH * KA2 * 2);
    unsigned short* X0b  = (unsigned short*)take((size_t)BATCH * KA2 * 2);
    unsigned short* X1a  = (unsigned short*)take((size_t)BATCH * KB * 2);
    unsigned short* X1b  = (unsigned short*)take((size_t)BATCH * KB * 2);
    // total ~131 MiB

    hipMemsetAsync(C1, 0, (size_t)BATCH * HID * 4, stream);
    hipMemsetAsync(C2, 0, (size_t)BATCH * HID * 4, stream);
    hipMemsetAsync(X0a, 0, (size_t)BATCH * KA2 * 2, stream);  // y0 = h1_0 = 0, pad = 0
    hipMemsetAsync(X0b, 0, (size_t)BATCH * KA2 * 2, stream);
    hipMemsetAsync(X1a, 0, (size_t)BATCH * KB * 2, stream);   // h2_0 = 0

    build_w0<<<5120, 256, 0, stream>>>(Wih0, Whh0, W0);
    build_w1<<<8192, 256, 0, stream>>>(Wih1, Whh1, W1);
    build_woutT<<<256, 256, 0, stream>>>(Wout, WoT);
    build_bias<<<16, 256, 0, stream>>>(bih0, bhh0, B0b);
    build_bias<<<16, 256, 0, stream>>>(bih1, bhh1, B1b);
    build_x0static<<<512, 256, 0, stream>>>(static_in, X0a, X0b);

    dim3 grid(16, 16);   // 256 blocks of 512 thr = 1 per CU
    for (int t = 0; t < TSTEPS; ++t) {
        unsigned short* X0c = (t & 1) ? X0b : X0a;
        unsigned short* X0n = (t & 1) ? X0a : X0b;
        unsigned short* X1c = (t & 1) ? X1b : X1a;
        unsigned short* X1n = (t & 1) ? X1a : X1b;
        // layer 0: gates = X0c @ W0^T + b0; h1 -> X1c[:,0:1024] and X0n[:,192:1216]
        lstm_gate_gemm<<<grid, 512, 0, stream>>>(X0c, KA2, W0, B0b, C1,
                                                 X1c, KB, 0, X0n, KA2, 192, nullptr);
        // layer 1: gates = X1c @ W1^T + b1; h2 -> X1n[:,1024:2048] + H2f
        lstm_gate_gemm<<<grid, 512, 0, stream>>>(X1c, KB, W1, B1b, C2,
                                                 X1n, KB, 1024, nullptr, 0, 0, H2f);
        // y_t = H2f @ WoutT + bout -> out[:,t,:] and X0n[:,0:64]
        out_gemm<<<256, 256, 0, stream>>>(H2f, WoT, bout, out + t * NOUT, X0n);
    }
}

// Round 7
// 3668.396 us; speedup vs baseline: 5.1273x; 1.3325x over previous
//
#include <hip/hip_runtime.h>

#define BATCH  4096
#define HID    1024
#define NOUT   64
#define TSTEPS 25
#define KA2    1280   // 64 (y_prev) + 128 (static) + 1024 (h1) + 64 zero-pad -> K % 64 == 0
#define KB     2048   // 1024 (h1) + 1024 (h2)
#define LDY    1600   // TSTEPS * NOUT

typedef __attribute__((ext_vector_type(8))) __bf16 bf16x8;
typedef __attribute__((ext_vector_type(4))) float  floatx4;

__device__ __forceinline__ unsigned short f2bf(float f) {
    union { float f; unsigned u; } v; v.f = f;
    unsigned r = v.u + 0x7fffu + ((v.u >> 16) & 1u);
    return (unsigned short)(r >> 16);
}
__device__ __forceinline__ float rcpf(float x) { return __builtin_amdgcn_rcpf(x); }
__device__ __forceinline__ float sigmf(float x) { return rcpf(1.0f + __expf(-x)); }
__device__ __forceinline__ float tanh_fast(float x) {
    float ax = fabsf(x);
    float e  = __expf(-2.0f * ax);
    float t  = (1.0f - e) * rcpf(1.0f + e);
    return copysignf(t, x);
}

#define GLDS16(gp, lp) __builtin_amdgcn_global_load_lds( \
    (const __attribute__((address_space(1))) void*)(gp), \
    (__attribute__((address_space(3))) void*)(lp), 16, 0, 0)

#define SB() __builtin_amdgcn_sched_barrier(0)

// v14 = v11 (best-known: 2-tiles-ahead staging, 4-phase counted vmcnt(6),
// phase-split MFMA, reg-prefetch one phase ahead, epilogue prefetch) with ONE
// change: MFMA loop order kk-OUTER. v11's fi->fj->kk order put the two MFMAs
// accumulating into the same acc[q][fi][fj] back-to-back (dependency distance
// 1); at 2 waves/SIMD the pipeline-latency stall between them is only half-
// covered. kk-outer gives distance 6-8 independent MFMAs. Per acc element the
// update sequence (kk=0 then kk=1) is unchanged -> bitwise-identical output.
// v13 post-mortem: B-direct-from-global regressed 66->98us (per-lane L2
// gathers inside the in-order stream at thin occupancy); operands must come
// from LDS. Reverted.
__global__ __launch_bounds__(512, 2) void lstm_gate_gemm(
    const unsigned short* __restrict__ X, int K,
    const unsigned short* __restrict__ W,
    const float* __restrict__ ginit,
    float* __restrict__ cell,
    unsigned short* __restrict__ d1, int ld1, int off1,
    unsigned short* __restrict__ d2, int ld2, int off2,
    float* __restrict__ dfp)
{
    // [buf0 | buf1], each: A0 @0, A1 @16K, B0 @32K, B1 @48K (16 KB half-tiles)
    __shared__ __align__(16) char smem[131072];

    const int tid  = threadIdx.x;
    const int lane = tid & 63;
    const int w    = tid >> 6;          // 0..7
    const int ql   = lane >> 4;         // 0..3 (K-chunk group of the frag)
    const int lr   = lane & 15;
    const int wr   = w >> 2;            // 0..1: 64-row half of the quadrant's 128
    const int wc   = w & 3;             // 0..3: 32-col slice of the quadrant's 128

    // XCD-aware swizzle (8 XCDs round-robin on flat block id)
    const int id  = blockIdx.y * 16 + blockIdx.x;
    const int xcd = id & 7;
    const int c   = id >> 3;
    const int bx  = (xcd & 3) * 4 + (c & 3);
    const int by  = (xcd >> 2) * 8 + (c >> 2);
    const int m0  = bx * 256;
    const int j0  = by * 64;

    // ---- staging sources: half-tile slot s = w*128 + lane (+64 for e=1)
    // slot s holds global chunk (row = s>>3, kc = (s&7)^(row&7)).
    const int s0  = w * 128 + lane;
    const int r0  = s0 >> 3;
    const int kc0 = (s0 & 7) ^ (r0 & 7);
    const unsigned sOff = (unsigned)s0 * 16;   // LDS byte offset within region (e=1: +1024)
    const unsigned short* sA[2];
    const unsigned short* sB[2];
    sA[0] = X + (size_t)(m0 + r0) * K + kc0 * 8;
    sA[1] = X + (size_t)(m0 + 128 + r0) * K + kc0 * 8;
    {
        const int nb0 = r0, nb1 = 128 + r0;    // B rows = gate-interleaved cols
        sB[0] = W + (size_t)((nb0 & 3) * HID + j0 + (nb0 >> 2)) * K + kc0 * 8;
        sB[1] = W + (size_t)((nb1 & 3) * HID + j0 + (nb1 >> 2)) * K + kc0 * 8;
    }

#define STAGE_A(h, tt, p) do { \
    const unsigned short* _s = sA[h] + (size_t)(tt) * 64; \
    char* _d = smem + (p) + (h) * 16384 + sOff; \
    GLDS16(_s, _d); \
    GLDS16(_s + 8 * (size_t)K, _d + 1024); \
} while (0)

#define STAGE_B(h, tt, p) do { \
    const unsigned short* _s = sB[h] + (size_t)(tt) * 64; \
    char* _d = smem + (p) + 32768 + (h) * 16384 + sOff; \
    GLDS16(_s, _d); \
    GLDS16(_s + 2 * (size_t)K, _d + 1024); \
} while (0)

    // ---- fragment ds_read offsets (relative to half-tile base; kk=1 -> ^64)
    unsigned offA[4], offB[2];
#pragma unroll
    for (int fi = 0; fi < 4; ++fi) {
        int r = wr * 64 + fi * 16 + lr;
        offA[fi] = (unsigned)((r * 8 + (ql ^ (r & 7))) * 16);
    }
#pragma unroll
    for (int fj = 0; fj < 2; ++fj) {
        int r = wc * 32 + fj * 16 + lr;
        offB[fj] = (unsigned)(32768 + (r * 8 + (ql ^ (r & 7))) * 16);
    }

#define LOAD_A(AV, BASE) do { \
    const char* _ab = smem + (BASE); \
    _Pragma("unroll") \
    for (int fi = 0; fi < 4; ++fi) { \
        AV[fi][0] = *(const bf16x8*)(_ab + offA[fi]); \
        AV[fi][1] = *(const bf16x8*)(_ab + (offA[fi] ^ 64u)); \
    } \
} while (0)

#define LOAD_B(BV, BASE) do { \
    const char* _bb = smem + (BASE); \
    _Pragma("unroll") \
    for (int fj = 0; fj < 2; ++fj) { \
        BV[fj][0] = *(const bf16x8*)(_bb + offB[fj]); \
        BV[fj][1] = *(const bf16x8*)(_bb + (offB[fj] ^ 64u)); \
    } \
} while (0)

// kk-OUTER: per acc element still kk=0 then kk=1 (bitwise identical), but
// dependent MFMA pairs are separated by 6-8 independent MFMAs.
#define MFMA_PART(Q, AV, BV, F0, F1) do { \
    __builtin_amdgcn_s_setprio(1); \
    _Pragma("unroll") \
    for (int kk = 0; kk < 2; ++kk) \
    _Pragma("unroll") \
    for (int fi = (F0); fi < (F1); ++fi) \
    _Pragma("unroll") \
    for (int fj = 0; fj < 2; ++fj) \
        acc[Q][fi][fj] = __builtin_amdgcn_mfma_f32_16x16x32_bf16( \
            AV[fi][kk], BV[fj][kk], acc[Q][fi][fj], 0, 0, 0); \
    __builtin_amdgcn_s_setprio(0); \
} while (0)

    floatx4 acc[4][4][2];   // [quadrant][fi][fj]; q: 0=(A0,B0) 1=(A0,B1) 2=(A1,B1) 3=(A1,B0)
#pragma unroll
    for (int q = 0; q < 4; ++q)
#pragma unroll
        for (int i = 0; i < 4; ++i)
#pragma unroll
            for (int j = 0; j < 2; ++j)
                acc[q][i][j] = floatx4{0.f, 0.f, 0.f, 0.f};

    const int NT = K >> 6;   // 64-wide K-tiles (20 or 32)

    bf16x8 av0[4][2], av1[4][2], bv0[2][2], bv1[2][2];

    // ---- prologue: stage tile0 -> buf0 (oldest in FIFO), tile1 -> buf1.
    STAGE_B(1, 0, 0); STAGE_A(1, 0, 0); STAGE_A(0, 0, 0); STAGE_B(0, 0, 0);
    STAGE_B(1, 1, 65536); STAGE_A(1, 1, 65536); STAGE_A(0, 1, 65536); STAGE_B(0, 1, 65536);
    asm volatile("s_waitcnt vmcnt(8)");      // tile0's 8 loads landed; tile1 in flight
    __builtin_amdgcn_s_barrier();
    SB();
    LOAD_A(av0, 0);          // buf0.A0(0)
    LOAD_B(bv0, 0);          // buf0.B0(0)
    LOAD_B(bv1, 16384);      // buf0.B1(0)
    SB();

    int par = 0;
    for (int t = 0; t < NT; ++t) {
        const int cur = par << 16;
        const int np  = cur ^ 65536;
        const int t2  = (t + 2 < NT) ? t + 2 : NT - 1;  // clamp: keeps vmcnt uniform
        // ---- P0: Q0 (av0 x bv0) | av1 <- cur.A1(t) | stage B1(t+2)->cur
        __builtin_amdgcn_s_barrier();
        SB();
        MFMA_PART(0, av0, bv0, 0, 1);
        SB();
        LOAD_A(av1, cur + 16384);
        STAGE_B(1, t2, cur);
        SB();
        MFMA_PART(0, av0, bv0, 1, 4);
        SB();
        // ---- P1: Q1 (av0 x bv1) | stage A1(t+2)->cur
        __builtin_amdgcn_s_barrier();
        SB();
        MFMA_PART(1, av0, bv1, 0, 1);
        SB();
        STAGE_A(1, t2, cur);
        SB();
        MFMA_PART(1, av0, bv1, 1, 4);
        SB();
        // ---- P2: Q2 (av1 x bv1) | av0 <- np.A0(t+1) | stage A0(t+2)->cur
        asm volatile("s_waitcnt vmcnt(6)");   // drains {B1,A1,A0}(t+1)
        __builtin_amdgcn_s_barrier();
        SB();
        MFMA_PART(2, av1, bv1, 0, 1);
        SB();
        LOAD_A(av0, np);
        STAGE_A(0, t2, cur);
        SB();
        MFMA_PART(2, av1, bv1, 1, 4);
        SB();
        // ---- P3: Q3 (av1 x bv0) | bv1 <- np.B1(t+1) | stage B0(t+2)->cur
        asm volatile("s_waitcnt vmcnt(6)");   // drains {B0}(t+1)
        __builtin_amdgcn_s_barrier();
        SB();
        MFMA_PART(3, av1, bv0, 0, 1);
        SB();
        LOAD_B(bv1, np + 16384);
        STAGE_B(0, t2, cur);
        SB();
        MFMA_PART(3, av1, bv0, 1, 4);
        SB();
        LOAD_B(bv0, np);     // bv0 regs freed by Q3; B0(t+1) landed (P3-top wait)
        par ^= 1;
    }

    // ---- epilogue: drain tail DMAs before reusing LDS as scratch.
    asm volatile("s_waitcnt vmcnt(0)");
    __builtin_amdgcn_s_barrier();

    // Per-wave private scratch (2560 B), padded stride 36 floats -> float4
    // reads conflict-free. No cross-wave sharing => no barriers, only
    // intra-wave compiler fences (HW orders same-wave LDS ops).
    float* scratch = (float*)(void*)smem + w * 640;
    const int jj   = lane & 7;
    const int rsel = lane >> 3;

    // Hoisted epilogue prefetch: cell + bias (operand regs dead here).
    float  cpre[4][4][2];
    float4 gi4[4];
#pragma unroll
    for (int qd = 0; qd < 4; ++qd) {
        const int qa = (qd >= 2) ? 1 : 0;
        const int qb = (qd == 1 || qd == 2) ? 1 : 0;
        const int rowbase = m0 + qa * 128 + wr * 64;
        const int jg = j0 + qb * 32 + wc * 8 + jj;
        gi4[qd] = *(const float4*)(ginit + (size_t)jg * 4);
#pragma unroll
        for (int fi = 0; fi < 4; ++fi)
#pragma unroll
            for (int p = 0; p < 2; ++p)
                cpre[qd][fi][p] = cell[(size_t)(rowbase + fi * 16 + rsel + p * 8) * HID + jg];
    }

#pragma unroll
    for (int qd = 0; qd < 4; ++qd) {
        const int qa = (qd >= 2) ? 1 : 0;
        const int qb = (qd == 1 || qd == 2) ? 1 : 0;
        const int rowbase = m0 + qa * 128 + wr * 64;
        const int jg = j0 + qb * 32 + wc * 8 + jj;
        const float4 gi = gi4[qd];
#pragma unroll
        for (int fi = 0; fi < 4; ++fi) {
            // 16x32 slab: C/D frag layout col=lane&15, row=ql*4+reg
#pragma unroll
            for (int fj = 0; fj < 2; ++fj)
#pragma unroll
                for (int r = 0; r < 4; ++r)
                    scratch[(ql * 4 + r) * 36 + fj * 16 + lr] = acc[qd][fi][fj][r];
            asm volatile("" ::: "memory");
#pragma unroll
            for (int p = 0; p < 2; ++p) {
                const int row = rsel + p * 8;
                const float4 g = *(const float4*)(scratch + row * 36 + jj * 4);
                const int b = rowbase + fi * 16 + row;
                float iv = sigmf(g.x + gi.x);
                float fv = sigmf(g.y + gi.y);
                float gv = tanh_fast(g.z + gi.z);
                float ov = sigmf(g.w + gi.w);
                size_t ci = (size_t)b * HID + jg;
                float cn = fv * cpre[qd][fi][p] + iv * gv;
                cell[ci] = cn;
                float hv = ov * tanh_fast(cn);
                unsigned short hb = f2bf(hv);
                d1[(size_t)b * ld1 + off1 + jg] = hb;
                if (d2)  d2[(size_t)b * ld2 + off2 + jg] = hb;
                if (dfp) dfp[(size_t)b * HID + jg] = hv;
            }
            asm volatile("" ::: "memory");
        }
    }
#undef MFMA_PART
#undef LOAD_A
#undef LOAD_B
#undef STAGE_A
#undef STAGE_B
}

// y = h2_f32 @ Wout^T + bout (fp32); WoutT layout wt[k*64+o]; h2 staged in LDS.
// 16 rows/block (256 blocks = 1/CU): halves device-wide WoT re-read traffic.
__global__ __launch_bounds__(256) void out_gemm(
    const float* __restrict__ h2, const float* __restrict__ wt,
    const float* __restrict__ bout, float* __restrict__ y,
    unsigned short* __restrict__ xn)
{
    __shared__ float hl[16 * 1024];   // 64 KB: 16 h2 rows
    const int tid = threadIdx.x;
    const int b0 = blockIdx.x * 16;
#pragma unroll
    for (int r = 0; r < 16; ++r) {
        int f4 = r * 256 + tid;
        *(float4*)(hl + f4 * 4) = *(const float4*)(h2 + (size_t)b0 * 1024 + f4 * 4);
    }
    __syncthreads();
    const int o  = tid & 63;
    const int wv = tid >> 6;          // 0..3, 4 rows each
    float a0 = 0.f, a1 = 0.f, a2 = 0.f, a3 = 0.f;
#pragma unroll 8
    for (int k = 0; k < 1024; ++k) {
        float wvv = wt[k * 64 + o];
        const float* hr = hl + (wv * 4) * 1024 + k;
        a0 += hr[0]    * wvv;
        a1 += hr[1024] * wvv;
        a2 += hr[2048] * wvv;
        a3 += hr[3072] * wvv;
    }
    float bo = bout[o];
    int b = b0 + wv * 4;
    float yv[4] = {a0 + bo, a1 + bo, a2 + bo, a3 + bo};
#pragma unroll
    for (int r = 0; r < 4; ++r) {
        y[(size_t)(b + r) * LDY + o] = yv[r];
        xn[(size_t)(b + r) * KA2 + o] = f2bf(yv[r]);
    }
}

// WoutT[k*64+o] = Wout[o*1024+k]
__global__ void build_woutT(const float* __restrict__ wout, float* __restrict__ wt)
{
    int idx = blockIdx.x * 256 + threadIdx.x;   // 65536
    int o = idx & 63, k = idx >> 6;
    wt[idx] = wout[(size_t)o * 1024 + k];
}

// interleaved bias: out[j*4+gate] = a[gate*1024+j] + b[gate*1024+j]
__global__ void build_bias(const float* __restrict__ a, const float* __restrict__ b,
                           float* __restrict__ o)
{
    int idx = blockIdx.x * 256 + threadIdx.x;   // 4096
    int gate = idx & 3, j = idx >> 2;
    int n = gate * 1024 + j;
    o[idx] = a[n] + b[n];
}

// W0[n] (KA2=1280): [0:64]=W_ih0[n][128:192], [64:192]=W_ih0[n][0:128],
// [192:1216]=W_hh0[n][:], [1216:1280]=0
__global__ __launch_bounds__(256) void build_w0(
    const float* __restrict__ wih, const float* __restrict__ whh,
    unsigned short* __restrict__ w0)
{
    int idx = blockIdx.x * 256 + threadIdx.x;   // 4096*320 exact
    int n = idx / 320;
    int c = (idx - n * 320) * 4;
    float4 v = {0.f, 0.f, 0.f, 0.f};
    if (c < 64)        v = *(const float4*)(wih + (size_t)n * 192 + 128 + c);
    else if (c < 192)  v = *(const float4*)(wih + (size_t)n * 192 + (c - 64));
    else if (c < 1216) v = *(const float4*)(whh + (size_t)n * 1024 + (c - 192));
    ushort4 o;
    o.x = f2bf(v.x); o.y = f2bf(v.y); o.z = f2bf(v.z); o.w = f2bf(v.w);
    *(ushort4*)(w0 + (size_t)n * KA2 + c) = o;
}

// W1[n][0:1024] = W_ih1[n][:], W1[n][1024:2048] = W_hh1[n][:]
__global__ __launch_bounds__(256) void build_w1(
    const float* __restrict__ wih, const float* __restrict__ whh,
    unsigned short* __restrict__ w1)
{
    int idx = blockIdx.x * 256 + threadIdx.x;   // 4096*512 exact
    int n = idx >> 9;
    int c = (idx & 511) * 4;
    float4 v;
    if (c < 1024) v = *(const float4*)(wih + (size_t)n * 1024 + c);
    else          v = *(const float4*)(whh + (size_t)n * 1024 + (c - 1024));
    ushort4 o;
    o.x = f2bf(v.x); o.y = f2bf(v.y); o.z = f2bf(v.z); o.w = f2bf(v.w);
    *(ushort4*)(w1 + (size_t)n * KB + c) = o;
}

// static bf16 into X0a and X0b cols 64..191
__global__ __launch_bounds__(256) void build_x0static(
    const float* __restrict__ stat, unsigned short* __restrict__ xa,
    unsigned short* __restrict__ xb)
{
    int idx = blockIdx.x * 256 + threadIdx.x;   // 4096*32 exact
    int b = idx >> 5;
    int c = (idx & 31) * 4;
    float4 v = *(const float4*)(stat + (size_t)b * 128 + c);
    ushort4 o;
    o.x = f2bf(v.x); o.y = f2bf(v.y); o.z = f2bf(v.z); o.w = f2bf(v.w);
    *(ushort4*)(xa + (size_t)b * KA2 + 64 + c) = o;
    *(ushort4*)(xb + (size_t)b * KA2 + 64 + c) = o;
}

extern "C" void kernel_launch(void* const* d_in, const int* in_sizes, int n_in,
                              void* d_out, int out_size, void* d_ws, size_t ws_size,
                              hipStream_t stream)
{
    (void)in_sizes; (void)n_in; (void)out_size; (void)ws_size;
    const float* static_in = (const float*)d_in[0];
    const float* Wih0 = (const float*)d_in[1];
    const float* Whh0 = (const float*)d_in[2];
    const float* bih0 = (const float*)d_in[3];
    const float* bhh0 = (const float*)d_in[4];
    const float* Wih1 = (const float*)d_in[5];
    const float* Whh1 = (const float*)d_in[6];
    const float* bih1 = (const float*)d_in[7];
    const float* bhh1 = (const float*)d_in[8];
    const float* Wout = (const float*)d_in[9];
    const float* bout = (const float*)d_in[10];
    float* out = (float*)d_out;

    char* p = (char*)d_ws;
    size_t off = 0;
    auto take = [&](size_t n) { char* r = p + off; off += (n + 255) & ~(size_t)255; return r; };

    unsigned short* W0   = (unsigned short*)take((size_t)4096 * KA2 * 2);
    unsigned short* W1   = (unsigned short*)take((size_t)4096 * KB * 2);
    float*          B1b  = (float*)take(4096 * 4);
    float*          B0b  = (float*)take(4096 * 4);
    float*          WoT  = (float*)take((size_t)1024 * 64 * 4);
    float*          H2f  = (float*)take((size_t)BATCH * HID * 4);
    float*          C1   = (float*)take((size_t)BATCH * HID * 4);
    float*          C2   = (float*)take((size_t)BATCH * HID * 4);
    unsigned short* X0a  = (unsigned short*)take((size_t)BATCH * KA2 * 2);
    unsigned short* X0b  = (unsigned short*)take((size_t)BATCH * KA2 * 2);
    unsigned short* X1a  = (unsigned short*)take((size_t)BATCH * KB * 2);
    unsigned short* X1b  = (unsigned short*)take((size_t)BATCH * KB * 2);
    // total ~131 MiB

    hipMemsetAsync(C1, 0, (size_t)BATCH * HID * 4, stream);
    hipMemsetAsync(C2, 0, (size_t)BATCH * HID * 4, stream);
    hipMemsetAsync(X0a, 0, (size_t)BATCH * KA2 * 2, stream);  // y0 = h1_0 = 0, pad = 0
    hipMemsetAsync(X0b, 0, (size_t)BATCH * KA2 * 2, stream);
    hipMemsetAsync(X1a, 0, (size_t)BATCH * KB * 2, stream);   // h2_0 = 0

    build_w0<<<5120, 256, 0, stream>>>(Wih0, Whh0, W0);
    build_w1<<<8192, 256, 0, stream>>>(Wih1, Whh1, W1);
    build_woutT<<<256, 256, 0, stream>>>(Wout, WoT);
    build_bias<<<16, 256, 0, stream>>>(bih0, bhh0, B0b);
    build_bias<<<16, 256, 0, stream>>>(bih1, bhh1, B1b);
    build_x0static<<<512, 256, 0, stream>>>(static_in, X0a, X0b);

    dim3 grid(16, 16);   // 256 blocks of 512 thr = 1 per CU (128 KB LDS)
    for (int t = 0; t < TSTEPS; ++t) {
        unsigned short* X0c = (t & 1) ? X0b : X0a;
        unsigned short* X0n = (t & 1) ? X0a : X0b;
        unsigned short* X1c = (t & 1) ? X1b : X1a;
        unsigned short* X1n = (t & 1) ? X1a : X1b;
        // layer 0: gates = X0c @ W0^T + b0; h1 -> X1c[:,0:1024] and X0n[:,192:1216]
        lstm_gate_gemm<<<grid, 512, 0, stream>>>(X0c, KA2, W0, B0b, C1,
                                                 X1c, KB, 0, X0n, KA2, 192, nullptr);
        // layer 1: gates = X1c @ W1^T + b1; h2 -> X1n[:,1024:2048] + H2f
        lstm_gate_gemm<<<grid, 512, 0, stream>>>(X1c, KB, W1, B1b, C2,
                                                 X1n, KB, 1024, nullptr, 0, 0, H2f);
        // y_t = H2f @ WoutT + bout -> out[:,t,:] and X0n[:,0:64]
        out_gemm<<<256, 256, 0, stream>>>(H2f, WoT, bout, out + t * NOUT, X0n);
    }
}